// Round 3
// baseline (261.674 us; speedup 1.0000x reference)
//
#include <hip/hip_runtime.h>

typedef __attribute__((ext_vector_type(8))) short short8;
typedef __attribute__((ext_vector_type(4))) float f32x4;
typedef __attribute__((ext_vector_type(2))) int int2v;
typedef __attribute__((ext_vector_type(4))) int int4v;

__device__ __forceinline__ short f2bf(float f) {
  unsigned u = __builtin_bit_cast(unsigned, f);
  u += 0x7fff + ((u >> 16) & 1);  // RNE
  return (short)(u >> 16);
}

__device__ __forceinline__ int pk2bf(float lo, float hi) {
#if defined(__gfx950__) && __has_builtin(__builtin_amdgcn_cvt_pk_bf16_f32)
  typedef __attribute__((ext_vector_type(2))) __bf16 bf16x2;
  bf16x2 v = __builtin_amdgcn_cvt_pk_bf16_f32(lo, hi);
  return __builtin_bit_cast(int, v);
#else
  return (int)(unsigned short)(short)f2bf(lo) | (((int)f2bf(hi)) << 16);
#endif
}

__device__ __forceinline__ short8 pack8(f32x4 a, f32x4 b) {
  int4v t;
  t.x = pk2bf(a[0], a[1]);
  t.y = pk2bf(a[2], a[3]);
  t.z = pk2bf(b[0], b[1]);
  t.w = pk2bf(b[2], b[3]);
  return __builtin_bit_cast(short8, t);
}

__device__ __forceinline__ float fand(float p, int m) {
  return __builtin_bit_cast(float, __builtin_bit_cast(int, p) & m);
}

__device__ __forceinline__ int bmask(unsigned nib, int bit) {
#if __has_builtin(__builtin_amdgcn_sbfe)
  return __builtin_amdgcn_sbfe((int)nib, bit, 1);  // 0 or 0xFFFFFFFF
#else
  return -(int)((nib >> bit) & 1);
#endif
}

__device__ __forceinline__ float fexp2(float x) {
#if __has_builtin(__builtin_amdgcn_exp2f)
  return __builtin_amdgcn_exp2f(x);
#else
  return exp2f(x);
#endif
}

// async global->LDS, 16B per lane; LDS dest = wave-uniform base + lane*16
__device__ __forceinline__ void glds16(const short* g, short* lbase, int lane) {
#if __has_builtin(__builtin_amdgcn_global_load_lds)
  __builtin_amdgcn_global_load_lds(
      (const __attribute__((address_space(1))) unsigned int*)g,
      (__attribute__((address_space(3))) unsigned int*)lbase, 16, 0, 0);
#else
  *(short8*)(lbase + lane * 8) = *(const short8*)g;
#endif
}

// =============== prep: projections + Wo cvt + mask pack, one dispatch ===============
// blocks [0,3072): per-head projections (mode = bid>>10: 0=Q(scaled),1=K,2=V^T sigma)
// blocks [3072,4096): Wo fp32->bf16
// blocks [4096,12288): mask bit-pack, sigma-permuted, 4 words/block-row
__global__ __launch_bounds__(256) void prep(const float* __restrict__ q,
                                            const float* __restrict__ k,
                                            const float* __restrict__ v,
                                            const float* __restrict__ Wq,
                                            const float* __restrict__ Wk,
                                            const float* __restrict__ Wv,
                                            const float* __restrict__ Wo,
                                            const int* __restrict__ mask,
                                            short* __restrict__ Qp,
                                            short* __restrict__ Kp,
                                            short* __restrict__ Vtp,
                                            short* __restrict__ Wob,
                                            unsigned long long* __restrict__ mpk) {
  const int bid = blockIdx.x;
  const int tid = threadIdx.x;

  if (bid >= 4096) {  // ---- mask pack: bit j = mask[.. + (j&3)*16 + (j>>2)] ----
#pragma unroll
    for (int it = 0; it < 4; ++it) {
      const int gid = ((bid - 4096) * 4 + it) * 256 + tid;
      const int base = gid & ~63, j = gid & 63;
      const int val = mask[base + ((j & 3) << 4) + (j >> 2)];
      const unsigned long long bal = __ballot(val != 0);
      if (j == 0) mpk[gid >> 6] = bal;
    }
    return;
  }
  if (bid >= 3072) {  // ---- Wo convert ----
    const int i = ((bid - 3072) * 256 + tid) * 4;
    const f32x4 x = *(const f32x4*)&Wo[i];
    int2v o;
    o.x = pk2bf(x[0], x[1]);
    o.y = pk2bf(x[2], x[3]);
    *(int2v*)&Wob[i] = o;
    return;
  }

  // ---- projection: Out = X @ W^T on a 64-row slab ----
  __shared__ short xt[64][72];
  __shared__ short ot[64][72];
  const int mode = bid >> 10;
  const int bt = bid & 1023;
  const float* X;
  const float* W;
  float scale;
  if (mode == 0) { X = q; W = Wq; scale = 0.045084220f; }  // log2(e)/32 folded into Q
  else if (mode == 1) { X = k; W = Wk; scale = 1.0f; }
  else { X = v; W = Wv; scale = 1.0f; }

  const int r0 = bt * 64;
  const int row = tid >> 2, seg = (tid & 3) * 16;
  const f32x4* xs = (const f32x4*)(X + (r0 + row) * 64 + seg);
  const f32x4 x0 = xs[0], x1 = xs[1], x2 = xs[2], x3 = xs[3];
  *(short8*)&xt[row][seg] = pack8(x0, x1);
  *(short8*)&xt[row][seg + 8] = pack8(x2, x3);
  __syncthreads();

  const int lane = tid & 63, wave = tid >> 6;
  const int m16 = lane & 15, quad = lane >> 4;

  const short8 a0 = *(const short8*)&xt[wave * 16 + m16][quad * 8];
  const short8 a1 = *(const short8*)&xt[wave * 16 + m16][32 + quad * 8];

  f32x4 acc[4];
#pragma unroll
  for (int nt = 0; nt < 4; ++nt) {
    const f32x4* wp0 = (const f32x4*)&W[(nt * 16 + m16) * 64 + quad * 8];
    const f32x4* wp1 = (const f32x4*)&W[(nt * 16 + m16) * 64 + 32 + quad * 8];
    const short8 b0 = pack8(wp0[0], wp0[1]);
    const short8 b1 = pack8(wp1[0], wp1[1]);
    f32x4 z = (f32x4){0.f, 0.f, 0.f, 0.f};
    z = __builtin_amdgcn_mfma_f32_16x16x32_bf16(a0, b0, z, 0, 0, 0);
    z = __builtin_amdgcn_mfma_f32_16x16x32_bf16(a1, b1, z, 0, 0, 0);
    acc[nt] = z;
  }

  // stage C-tile in LDS so global stores are b128-coalesced
  if (mode != 2) {
#pragma unroll
    for (int nt = 0; nt < 4; ++nt)
#pragma unroll
      for (int r = 0; r < 4; ++r)
        ot[wave * 16 + quad * 4 + r][nt * 16 + m16] = f2bf(acc[nt][r] * scale);
  } else {
    // transposed + sigma-permuted: ot[d][sigma(key)], sigma = 16*quad + 4*r + wave
#pragma unroll
    for (int nt = 0; nt < 4; ++nt)
#pragma unroll
      for (int r = 0; r < 4; ++r)
        ot[nt * 16 + m16][16 * quad + 4 * r + wave] = f2bf(acc[nt][r]);
  }
  __syncthreads();

  const int orow = tid >> 2, opart = tid & 3;
  if (mode != 2) {
    short* dst = (mode == 0 ? Qp : Kp) + (r0 + orow) * 64 + opart * 16;
    *(short8*)&dst[0] = *(const short8*)&ot[orow][opart * 16];
    *(short8*)&dst[8] = *(const short8*)&ot[orow][opart * 16 + 8];
  } else {
    const int bh = r0 >> 11, s0 = r0 & 2047;
    short* dst = Vtp + bh * 131072 + orow * 2048 + s0 + opart * 16;
    *(short8*)&dst[0] = *(const short8*)&ot[orow][opart * 16];
    *(short8*)&dst[8] = *(const short8*)&ot[orow][opart * 16 + 8];
  }
}

// =============== flash attention: 128 q-rows/block, glds-staged K/V ===============
// Qp (pre-scaled): [BH][2048][64]; Kp: [BH][2048][64]; Vt: [BH][64][2048] sigma-ordered;
// mpk: [B][2048][32] u64 sigma-ordered bits; O: [BH][2048][64] bf16.
// kt/vt: unpadded 64x64 tiles, 16B-block XOR swizzle slot = j ^ (row&7).
__global__ __launch_bounds__(256) void flash128(const short* __restrict__ Qp,
                                                const short* __restrict__ Kp,
                                                const short* __restrict__ Vt,
                                                const unsigned long long* __restrict__ mpk,
                                                short* __restrict__ O) {
  __shared__ __attribute__((aligned(16))) short kt[4096];
  __shared__ __attribute__((aligned(16))) short vt[4096];
  __shared__ __attribute__((aligned(16))) short pt[128][72];
  const int tid = threadIdx.x;
  const int bid = blockIdx.x;
  // XCD-grouping: blocks with equal bid%8 share 4 heads
  const int local = bid >> 3;
  const int bh = (bid & 7) * 4 + (local >> 4);
  const int q0 = (local & 15) << 7;
  const int b = bh >> 4;
  const short* Qh = Qp + bh * 131072;
  const short* Kh = Kp + bh * 131072;
  const short* Vh = Vt + bh * 131072;
  const int lane = tid & 63, wave = tid >> 6;
  const int m16 = lane & 15, quad = lane >> 4;
  const int srow = lane >> 3, sj = (lane & 7) ^ srow;  // staging row-in-chunk / swizzled src block
  const int msh = m16 * 4;
  const int koff = m16 * 128 + ((quad ^ (m16 & 7)) * 16);  // byte offset of b128 frag read

  short8 aq[2][2];
#pragma unroll
  for (int g = 0; g < 2; ++g)
#pragma unroll
    for (int h = 0; h < 2; ++h)
      aq[g][h] = *(const short8*)&Qh[(q0 + wave * 32 + g * 16 + m16) * 64 + h * 32 + quad * 8];

  const unsigned long long* mq = mpk + (b * 2048 + q0 + wave * 32 + quad * 4) * 32;

  float l[2][4];
  f32x4 oacc[2][4];
#pragma unroll
  for (int g = 0; g < 2; ++g)
#pragma unroll
    for (int r = 0; r < 4; ++r) l[g][r] = 0.f;
#pragma unroll
  for (int g = 0; g < 2; ++g)
#pragma unroll
    for (int dt = 0; dt < 4; ++dt) oacc[g][dt] = (f32x4){0.f, 0.f, 0.f, 0.f};

  for (int kti = 0; kti < 32; ++kti) {
    const int k0 = kti << 6;
    __syncthreads();
#pragma unroll
    for (int t = 0; t < 2; ++t) {
      const int crow = wave * 16 + t * 8;        // chunk base row (wave-uniform)
      const int grow = crow + srow;              // this lane's source row
      glds16(Kh + (k0 + grow) * 64 + sj * 8, kt + crow * 64, lane);
      glds16(Vh + grow * 2048 + k0 + sj * 8, vt + crow * 64, lane);
    }
    __syncthreads();

    // S = Q K^T
    f32x4 s[2][4];
#pragma unroll
    for (int nt = 0; nt < 4; ++nt) {
      const int o0 = nt * 2048 + koff;
      const short8 kb0 = *(const short8*)((const char*)kt + o0);
      const short8 kb1 = *(const short8*)((const char*)kt + (o0 ^ 64));
#pragma unroll
      for (int g = 0; g < 2; ++g) {
        f32x4 z = (f32x4){0.f, 0.f, 0.f, 0.f};
        z = __builtin_amdgcn_mfma_f32_16x16x32_bf16(aq[g][0], kb0, z, 0, 0, 0);
        z = __builtin_amdgcn_mfma_f32_16x16x32_bf16(aq[g][1], kb1, z, 0, 0, 0);
        s[g][nt] = z;
      }
    }

    // p = exp2(s) & mask; per-lane l; P -> LDS (bf16, sigma cols)
#pragma unroll
    for (int g = 0; g < 2; ++g) {
#pragma unroll
      for (int r = 0; r < 4; ++r) {
        const unsigned long long w = mq[g * 512 + r * 32 + kti];
        const unsigned nib = (unsigned)(w >> msh) & 15u;
        const float p0 = fand(fexp2(s[g][0][r]), bmask(nib, 0));
        const float p1 = fand(fexp2(s[g][1][r]), bmask(nib, 1));
        const float p2 = fand(fexp2(s[g][2][r]), bmask(nib, 2));
        const float p3 = fand(fexp2(s[g][3][r]), bmask(nib, 3));
        l[g][r] += (p0 + p1) + (p2 + p3);
        int2v pp;
        pp.x = pk2bf(p0, p1);
        pp.y = pk2bf(p2, p3);
        *(int2v*)&pt[wave * 32 + g * 16 + quad * 4 + r][msh] = pp;
      }
    }

    // O += P V (same-wave DS in-order: no barrier for pt)
    short8 ap[2][2];
#pragma unroll
    for (int g = 0; g < 2; ++g)
#pragma unroll
      for (int h = 0; h < 2; ++h)
        ap[g][h] = *(const short8*)&pt[wave * 32 + g * 16 + m16][h * 32 + quad * 8];

#pragma unroll
    for (int dt = 0; dt < 4; ++dt) {
      const int o0 = dt * 2048 + koff;
      const short8 vb0 = *(const short8*)((const char*)vt + o0);
      const short8 vb1 = *(const short8*)((const char*)vt + (o0 ^ 64));
#pragma unroll
      for (int g = 0; g < 2; ++g) {
        f32x4 z = oacc[g][dt];
        z = __builtin_amdgcn_mfma_f32_16x16x32_bf16(ap[g][0], vb0, z, 0, 0, 0);
        z = __builtin_amdgcn_mfma_f32_16x16x32_bf16(ap[g][1], vb1, z, 0, 0, 0);
        oacc[g][dt] = z;
      }
    }
  }

  // l reduction (16-lane groups), normalize, coalesced O store via pt
#pragma unroll
  for (int g = 0; g < 2; ++g)
#pragma unroll
    for (int r = 0; r < 4; ++r) {
#pragma unroll
      for (int off = 1; off < 16; off <<= 1) l[g][r] += __shfl_xor(l[g][r], off, 16);
      const float inv = 1.0f / l[g][r];
#pragma unroll
      for (int dt = 0; dt < 4; ++dt)
        pt[wave * 32 + g * 16 + quad * 4 + r][dt * 16 + m16] = f2bf(oacc[g][dt][r] * inv);
    }

  const int orow = lane >> 1, opart = lane & 1;
  const int prow = wave * 32 + orow;
  short* og = O + (bh * 2048 + q0 + prow) * 64 + opart * 32;
#pragma unroll
  for (int c = 0; c < 32; c += 8)
    *(short8*)&og[c] = *(const short8*)&pt[prow][opart * 32 + c];
}

// =============== final projection: out = O @ Wo^T + bo, 128x128 tiles ===============
__global__ __launch_bounds__(256) void outproj(const short* __restrict__ Ob,
                                               const short* __restrict__ Wob,
                                               const float* __restrict__ bo,
                                               float* __restrict__ out) {
  __shared__ short at[128][72];
  __shared__ short bt[128][72];
  const int tid = threadIdx.x;
  const int bid = blockIdx.x;
  const int ct = bid & 7, rt = bid >> 3;
  const int r0 = rt * 128, c0 = ct * 128;
  const int lane = tid & 63, wave = tid >> 6;
  const int wr = (wave >> 1) * 64, wc = (wave & 1) * 64;
  const int m16 = lane & 15, quad = lane >> 4;
  const int srow = tid >> 1, shalf = (tid & 1) * 32;

  f32x4 acc[4][4];
#pragma unroll
  for (int mt = 0; mt < 4; ++mt)
#pragma unroll
    for (int nt = 0; nt < 4; ++nt) acc[mt][nt] = (f32x4){0.f, 0.f, 0.f, 0.f};

  for (int kc = 0; kc < 16; ++kc) {
    __syncthreads();
    const short* ag = &Ob[(r0 + srow) * 1024 + kc * 64 + shalf];
    const short* bg = &Wob[(c0 + srow) * 1024 + kc * 64 + shalf];
    *(short8*)&at[srow][shalf] = *(const short8*)&ag[0];
    *(short8*)&at[srow][shalf + 8] = *(const short8*)&ag[8];
    *(short8*)&at[srow][shalf + 16] = *(const short8*)&ag[16];
    *(short8*)&at[srow][shalf + 24] = *(const short8*)&ag[24];
    *(short8*)&bt[srow][shalf] = *(const short8*)&bg[0];
    *(short8*)&bt[srow][shalf + 8] = *(const short8*)&bg[8];
    *(short8*)&bt[srow][shalf + 16] = *(const short8*)&bg[16];
    *(short8*)&bt[srow][shalf + 24] = *(const short8*)&bg[24];
    __syncthreads();

#pragma unroll
    for (int kh = 0; kh < 2; ++kh) {
      short8 af[4], bf[4];
#pragma unroll
      for (int i = 0; i < 4; ++i) {
        af[i] = *(const short8*)&at[wr + i * 16 + m16][kh * 32 + quad * 8];
        bf[i] = *(const short8*)&bt[wc + i * 16 + m16][kh * 32 + quad * 8];
      }
#pragma unroll
      for (int mt = 0; mt < 4; ++mt)
#pragma unroll
        for (int nt = 0; nt < 4; ++nt)
          acc[mt][nt] = __builtin_amdgcn_mfma_f32_16x16x32_bf16(af[mt], bf[nt], acc[mt][nt], 0, 0, 0);
    }
  }

#pragma unroll
  for (int nt = 0; nt < 4; ++nt) {
    const int col = c0 + wc + nt * 16 + m16;
    const float bias = bo[col];
#pragma unroll
    for (int mt = 0; mt < 4; ++mt)
#pragma unroll
      for (int rr = 0; rr < 4; ++rr)
        out[(r0 + wr + mt * 16 + quad * 4 + rr) * 1024 + col] = acc[mt][nt][rr] + bias;
  }
}

// ---------------- launch ----------------
extern "C" void kernel_launch(void* const* d_in, const int* in_sizes, int n_in,
                              void* d_out, int out_size, void* d_ws, size_t ws_size,
                              hipStream_t stream) {
  const float* query = (const float*)d_in[0];
  const float* key = (const float*)d_in[1];
  const float* value = (const float*)d_in[2];
  const int* mask = (const int*)d_in[3];
  const float* Wq = (const float*)d_in[4];
  const float* Wk = (const float*)d_in[5];
  const float* Wv = (const float*)d_in[6];
  const float* Wo = (const float*)d_in[7];
  const float* bo = (const float*)d_in[8];
  float* out = (float*)d_out;

  char* ws = (char*)d_ws;
  short* Qp = (short*)(ws);
  short* Kp = (short*)(ws + 8388608);
  short* Vt = (short*)(ws + 16777216);
  short* Ob = (short*)(ws + 25165824);
  short* Wob = (short*)(ws + 33554432);
  unsigned long long* mpk = (unsigned long long*)(ws + 35651584);  // 1 MB

  prep<<<12288, 256, 0, stream>>>(query, key, value, Wq, Wk, Wv, Wo, mask,
                                  Qp, Kp, Vt, Wob, mpk);
  flash128<<<512, 256, 0, stream>>>(Qp, Kp, Vt, mpk, Ob);
  outproj<<<256, 256, 0, stream>>>(Ob, Wob, bo, out);
}

// Round 4
// 253.360 us; speedup vs baseline: 1.0328x; 1.0328x over previous
//
#include <hip/hip_runtime.h>

typedef __attribute__((ext_vector_type(8))) short short8;
typedef __attribute__((ext_vector_type(4))) float f32x4;
typedef __attribute__((ext_vector_type(2))) int int2v;
typedef __attribute__((ext_vector_type(4))) int int4v;

__device__ __forceinline__ short f2bf(float f) {
  unsigned u = __builtin_bit_cast(unsigned, f);
  u += 0x7fff + ((u >> 16) & 1);  // RNE
  return (short)(u >> 16);
}

__device__ __forceinline__ int pk2bf(float lo, float hi) {
#if defined(__gfx950__) && __has_builtin(__builtin_amdgcn_cvt_pk_bf16_f32)
  typedef __attribute__((ext_vector_type(2))) __bf16 bf16x2;
  bf16x2 v = __builtin_amdgcn_cvt_pk_bf16_f32(lo, hi);
  return __builtin_bit_cast(int, v);
#else
  return (int)(unsigned short)(short)f2bf(lo) | (((int)f2bf(hi)) << 16);
#endif
}

__device__ __forceinline__ short8 pack8(f32x4 a, f32x4 b) {
  int4v t;
  t.x = pk2bf(a[0], a[1]);
  t.y = pk2bf(a[2], a[3]);
  t.z = pk2bf(b[0], b[1]);
  t.w = pk2bf(b[2], b[3]);
  return __builtin_bit_cast(short8, t);
}

__device__ __forceinline__ float fand(float p, int m) {
  return __builtin_bit_cast(float, __builtin_bit_cast(int, p) & m);
}

__device__ __forceinline__ int bmask(unsigned nib, int bit) {
#if __has_builtin(__builtin_amdgcn_sbfe)
  return __builtin_amdgcn_sbfe((int)nib, bit, 1);  // 0 or 0xFFFFFFFF
#else
  return -(int)((nib >> bit) & 1);
#endif
}

__device__ __forceinline__ float fexp2(float x) {
#if __has_builtin(__builtin_amdgcn_exp2f)
  return __builtin_amdgcn_exp2f(x);
#else
  return exp2f(x);
#endif
}

// async global->LDS, 16B per lane; LDS dest = wave-uniform base + lane*16
__device__ __forceinline__ void glds16(const short* g, short* lbase, int lane) {
#if __has_builtin(__builtin_amdgcn_global_load_lds)
  __builtin_amdgcn_global_load_lds(
      (const __attribute__((address_space(1))) unsigned int*)g,
      (__attribute__((address_space(3))) unsigned int*)lbase, 16, 0, 0);
#else
  *(short8*)(lbase + lane * 8) = *(const short8*)g;
#endif
}

// =============== prep: projections + Wo cvt + mask pack, one dispatch ===============
__global__ __launch_bounds__(256) void prep(const float* __restrict__ q,
                                            const float* __restrict__ k,
                                            const float* __restrict__ v,
                                            const float* __restrict__ Wq,
                                            const float* __restrict__ Wk,
                                            const float* __restrict__ Wv,
                                            const float* __restrict__ Wo,
                                            const int* __restrict__ mask,
                                            short* __restrict__ Qp,
                                            short* __restrict__ Kp,
                                            short* __restrict__ Vtp,
                                            short* __restrict__ Wob,
                                            unsigned long long* __restrict__ mpk) {
  const int bid = blockIdx.x;
  const int tid = threadIdx.x;

  if (bid >= 4096) {  // ---- mask pack: bit j = mask[.. + (j&3)*16 + (j>>2)] ----
#pragma unroll
    for (int it = 0; it < 4; ++it) {
      const int gid = ((bid - 4096) * 4 + it) * 256 + tid;
      const int base = gid & ~63, j = gid & 63;
      const int val = mask[base + ((j & 3) << 4) + (j >> 2)];
      const unsigned long long bal = __ballot(val != 0);
      if (j == 0) mpk[gid >> 6] = bal;
    }
    return;
  }
  if (bid >= 3072) {  // ---- Wo convert ----
    const int i = ((bid - 3072) * 256 + tid) * 4;
    const f32x4 x = *(const f32x4*)&Wo[i];
    int2v o;
    o.x = pk2bf(x[0], x[1]);
    o.y = pk2bf(x[2], x[3]);
    *(int2v*)&Wob[i] = o;
    return;
  }

  // ---- projection: Out = X @ W^T on a 64-row slab ----
  __shared__ short xt[64][72];
  __shared__ short ot[64][72];
  const int mode = bid >> 10;
  const int bt = bid & 1023;
  const float* X;
  const float* W;
  float scale;
  if (mode == 0) { X = q; W = Wq; scale = 0.045084220f; }  // log2(e)/32 folded into Q
  else if (mode == 1) { X = k; W = Wk; scale = 1.0f; }
  else { X = v; W = Wv; scale = 1.0f; }

  const int r0 = bt * 64;
  const int row = tid >> 2, seg = (tid & 3) * 16;
  const f32x4* xs = (const f32x4*)(X + (r0 + row) * 64 + seg);
  const f32x4 x0 = xs[0], x1 = xs[1], x2 = xs[2], x3 = xs[3];
  *(short8*)&xt[row][seg] = pack8(x0, x1);
  *(short8*)&xt[row][seg + 8] = pack8(x2, x3);
  __syncthreads();

  const int lane = tid & 63, wave = tid >> 6;
  const int m16 = lane & 15, quad = lane >> 4;

  const short8 a0 = *(const short8*)&xt[wave * 16 + m16][quad * 8];
  const short8 a1 = *(const short8*)&xt[wave * 16 + m16][32 + quad * 8];

  f32x4 acc[4];
#pragma unroll
  for (int nt = 0; nt < 4; ++nt) {
    const f32x4* wp0 = (const f32x4*)&W[(nt * 16 + m16) * 64 + quad * 8];
    const f32x4* wp1 = (const f32x4*)&W[(nt * 16 + m16) * 64 + 32 + quad * 8];
    const short8 b0 = pack8(wp0[0], wp0[1]);
    const short8 b1 = pack8(wp1[0], wp1[1]);
    f32x4 z = (f32x4){0.f, 0.f, 0.f, 0.f};
    z = __builtin_amdgcn_mfma_f32_16x16x32_bf16(a0, b0, z, 0, 0, 0);
    z = __builtin_amdgcn_mfma_f32_16x16x32_bf16(a1, b1, z, 0, 0, 0);
    acc[nt] = z;
  }

  if (mode != 2) {
#pragma unroll
    for (int nt = 0; nt < 4; ++nt)
#pragma unroll
      for (int r = 0; r < 4; ++r)
        ot[wave * 16 + quad * 4 + r][nt * 16 + m16] = f2bf(acc[nt][r] * scale);
  } else {
    // transposed + sigma-permuted: ot[d][sigma(key)], sigma = 16*quad + 4*r + wave
#pragma unroll
    for (int nt = 0; nt < 4; ++nt)
#pragma unroll
      for (int r = 0; r < 4; ++r)
        ot[nt * 16 + m16][16 * quad + 4 * r + wave] = f2bf(acc[nt][r]);
  }
  __syncthreads();

  const int orow = tid >> 2, opart = tid & 3;
  if (mode != 2) {
    short* dst = (mode == 0 ? Qp : Kp) + (r0 + orow) * 64 + opart * 16;
    *(short8*)&dst[0] = *(const short8*)&ot[orow][opart * 16];
    *(short8*)&dst[8] = *(const short8*)&ot[orow][opart * 16 + 8];
  } else {
    const int bh = r0 >> 11, s0 = r0 & 2047;
    short* dst = Vtp + bh * 131072 + orow * 2048 + s0 + opart * 16;
    *(short8*)&dst[0] = *(const short8*)&ot[orow][opart * 16];
    *(short8*)&dst[8] = *(const short8*)&ot[orow][opart * 16 + 8];
  }
}

// =============== flash2: 128 q-rows, in-block K-split (8 waves: 2 halves) ===========
// Qp (pre-scaled): [BH][2048][64]; Kp: [BH][2048][64]; Vt: [BH][64][2048] sigma-ordered;
// mpk: [B][2048][32] u64 sigma bits; O: [BH][2048][64] bf16.
// Waves 0-3: k-tiles 0-15; waves 4-7: k-tiles 16-31; combine via LDS at end.
__global__ __launch_bounds__(512) void flash2(const short* __restrict__ Qp,
                                              const short* __restrict__ Kp,
                                              const short* __restrict__ Vt,
                                              const unsigned long long* __restrict__ mpk,
                                              short* __restrict__ O) {
  __shared__ __attribute__((aligned(16))) short kv[4][4096];   // K_A,V_A,K_B,V_B
  __shared__ __attribute__((aligned(16))) short pt[2][128][72];
  __shared__ float lbuf[128];
  const int tid = threadIdx.x;
  const int bid = blockIdx.x;
  const int local = bid >> 3;               // XCD-grouping
  const int bh = (bid & 7) * 4 + (local >> 4);
  const int q0 = (local & 15) << 7;
  const int b = bh >> 4;
  const short* Qh = Qp + bh * 131072;
  const short* Kh = Kp + bh * 131072;
  const short* Vh = Vt + bh * 131072;
  const int lane = tid & 63, wave = tid >> 6;
  const int half = wave >> 2, wq = wave & 3;
  const int m16 = lane & 15, quad = lane >> 4;
  const int srow = lane >> 3, sj = (lane & 7) ^ srow;
  const int msh = m16 * 4;
  const int koff = m16 * 128 + ((quad ^ (m16 & 7)) * 16);
  short* ktb = &kv[half * 2][0];
  short* vtb = &kv[half * 2 + 1][0];
  // staging role: tsel 0 -> K tile, 1 -> V tile; each wave covers 32 rows of one tile
  const int tsel = wq >> 1, rbase = (wq & 1) * 32;

  short8 aq[2][2];
#pragma unroll
  for (int g = 0; g < 2; ++g)
#pragma unroll
    for (int h = 0; h < 2; ++h)
      aq[g][h] = *(const short8*)&Qh[(q0 + wq * 32 + g * 16 + m16) * 64 + h * 32 + quad * 8];

  const unsigned long long* mq = mpk + (b * 2048 + q0 + wq * 32 + quad * 4) * 32;

  float l[2][4];
  f32x4 oacc[2][4];
#pragma unroll
  for (int g = 0; g < 2; ++g)
#pragma unroll
    for (int r = 0; r < 4; ++r) l[g][r] = 0.f;
#pragma unroll
  for (int g = 0; g < 2; ++g)
#pragma unroll
    for (int dt = 0; dt < 4; ++dt) oacc[g][dt] = (f32x4){0.f, 0.f, 0.f, 0.f};

  for (int i = 0; i < 16; ++i) {
    const int ka = half * 16 + i;
    const int k0 = ka << 6;
    __syncthreads();
#pragma unroll
    for (int t = 0; t < 4; ++t) {
      const int crow = rbase + t * 8;
      if (tsel == 0)
        glds16(Kh + (k0 + crow + srow) * 64 + sj * 8, ktb + crow * 64, lane);
      else
        glds16(Vh + (crow + srow) * 2048 + k0 + sj * 8, vtb + crow * 64, lane);
    }
    __syncthreads();

    // S = Q K^T
    f32x4 s[2][4];
#pragma unroll
    for (int nt = 0; nt < 4; ++nt) {
      const int o0 = nt * 2048 + koff;
      const short8 kb0 = *(const short8*)((const char*)ktb + o0);
      const short8 kb1 = *(const short8*)((const char*)ktb + (o0 ^ 64));
#pragma unroll
      for (int g = 0; g < 2; ++g) {
        f32x4 z = (f32x4){0.f, 0.f, 0.f, 0.f};
        z = __builtin_amdgcn_mfma_f32_16x16x32_bf16(aq[g][0], kb0, z, 0, 0, 0);
        z = __builtin_amdgcn_mfma_f32_16x16x32_bf16(aq[g][1], kb1, z, 0, 0, 0);
        s[g][nt] = z;
      }
    }

    // p = exp2(s) & mask; per-lane l; P -> LDS (bf16, sigma cols)
#pragma unroll
    for (int g = 0; g < 2; ++g) {
#pragma unroll
      for (int r = 0; r < 4; ++r) {
        const unsigned long long w = mq[g * 512 + r * 32 + ka];
        const unsigned nib = (unsigned)(w >> msh) & 15u;
        const float p0 = fand(fexp2(s[g][0][r]), bmask(nib, 0));
        const float p1 = fand(fexp2(s[g][1][r]), bmask(nib, 1));
        const float p2 = fand(fexp2(s[g][2][r]), bmask(nib, 2));
        const float p3 = fand(fexp2(s[g][3][r]), bmask(nib, 3));
        l[g][r] += (p0 + p1) + (p2 + p3);
        int2v pp;
        pp.x = pk2bf(p0, p1);
        pp.y = pk2bf(p2, p3);
        *(int2v*)&pt[half][wq * 32 + g * 16 + quad * 4 + r][msh] = pp;
      }
    }

    // O += P V (same-wave DS ordering: no barrier for pt)
    short8 ap[2][2];
#pragma unroll
    for (int g = 0; g < 2; ++g)
#pragma unroll
      for (int h = 0; h < 2; ++h)
        ap[g][h] = *(const short8*)&pt[half][wq * 32 + g * 16 + m16][h * 32 + quad * 8];

#pragma unroll
    for (int dt = 0; dt < 4; ++dt) {
      const int o0 = dt * 2048 + koff;
      const short8 vb0 = *(const short8*)((const char*)vtb + o0);
      const short8 vb1 = *(const short8*)((const char*)vtb + (o0 ^ 64));
#pragma unroll
      for (int g = 0; g < 2; ++g) {
        f32x4 z = oacc[g][dt];
        z = __builtin_amdgcn_mfma_f32_16x16x32_bf16(ap[g][0], vb0, z, 0, 0, 0);
        z = __builtin_amdgcn_mfma_f32_16x16x32_bf16(ap[g][1], vb1, z, 0, 0, 0);
        oacc[g][dt] = z;
      }
    }
  }

  // l reduction within each half (16-lane groups)
#pragma unroll
  for (int g = 0; g < 2; ++g)
#pragma unroll
    for (int r = 0; r < 4; ++r)
#pragma unroll
      for (int off = 1; off < 16; off <<= 1) l[g][r] += __shfl_xor(l[g][r], off, 16);

  __syncthreads();  // all MFMA reads of kv done; halves in sync

  if (half == 1) {  // export partial O (raw sums) + partial l via LDS
    float* obuf = (float*)kv;
#pragma unroll
    for (int g = 0; g < 2; ++g)
#pragma unroll
      for (int r = 0; r < 4; ++r) {
        const int row = wq * 32 + g * 16 + quad * 4 + r;
#pragma unroll
        for (int dt = 0; dt < 4; ++dt) obuf[row * 64 + dt * 16 + m16] = oacc[g][dt][r];
        if (m16 == 0) lbuf[row] = l[g][r];
      }
  }
  __syncthreads();

  if (half == 0) {  // combine, normalize, coalesced store via pt[0]
    const float* obuf = (const float*)kv;
#pragma unroll
    for (int g = 0; g < 2; ++g)
#pragma unroll
      for (int r = 0; r < 4; ++r) {
        const int row = wq * 32 + g * 16 + quad * 4 + r;
        const float inv = 1.0f / (l[g][r] + lbuf[row]);
#pragma unroll
        for (int dt = 0; dt < 4; ++dt)
          pt[0][row][dt * 16 + m16] =
              f2bf((oacc[g][dt][r] + obuf[row * 64 + dt * 16 + m16]) * inv);
      }
    const int orow = lane >> 1, opart = lane & 1;
    const int prow = wq * 32 + orow;
    short* og = O + (bh * 2048 + q0 + prow) * 64 + opart * 32;
#pragma unroll
    for (int c = 0; c < 32; c += 8)
      *(short8*)&og[c] = *(const short8*)&pt[0][prow][opart * 32 + c];
  }
}

// =============== final projection: out = O @ Wo^T + bo, 64x128 tiles ===============
__global__ __launch_bounds__(256) void outproj(const short* __restrict__ Ob,
                                               const short* __restrict__ Wob,
                                               const float* __restrict__ bo,
                                               float* __restrict__ out) {
  __shared__ short at[64][72];
  __shared__ short bt[128][72];
  const int tid = threadIdx.x;
  const int bid = blockIdx.x;
  const int ct = bid >> 6, rt = bid & 63;  // ct-major: consecutive bids share Wob slab
  const int r0 = rt * 64, c0 = ct * 128;
  const int lane = tid & 63, wave = tid >> 6;
  const int mr = (wave >> 1) * 32, nc = (wave & 1) * 64;
  const int m16 = lane & 15, quad = lane >> 4;
  const int arow = tid >> 2, apart = tid & 3;     // A staging: 64 rows x 4 parts
  const int brow = tid >> 1, bhalf = (tid & 1) * 32;  // B staging: 128 rows x 2 halves

  f32x4 acc[2][4];
#pragma unroll
  for (int mt = 0; mt < 2; ++mt)
#pragma unroll
    for (int nt = 0; nt < 4; ++nt) acc[mt][nt] = (f32x4){0.f, 0.f, 0.f, 0.f};

  for (int kc = 0; kc < 16; ++kc) {
    __syncthreads();
    const short* ag = &Ob[(r0 + arow) * 1024 + kc * 64 + apart * 16];
    const short* bg = &Wob[(c0 + brow) * 1024 + kc * 64 + bhalf];
    *(short8*)&at[arow][apart * 16] = *(const short8*)&ag[0];
    *(short8*)&at[arow][apart * 16 + 8] = *(const short8*)&ag[8];
    *(short8*)&bt[brow][bhalf] = *(const short8*)&bg[0];
    *(short8*)&bt[brow][bhalf + 8] = *(const short8*)&bg[8];
    *(short8*)&bt[brow][bhalf + 16] = *(const short8*)&bg[16];
    *(short8*)&bt[brow][bhalf + 24] = *(const short8*)&bg[24];
    __syncthreads();

#pragma unroll
    for (int kh = 0; kh < 2; ++kh) {
      short8 af[2], bf[4];
#pragma unroll
      for (int i = 0; i < 2; ++i)
        af[i] = *(const short8*)&at[mr + i * 16 + m16][kh * 32 + quad * 8];
#pragma unroll
      for (int j = 0; j < 4; ++j)
        bf[j] = *(const short8*)&bt[nc + j * 16 + m16][kh * 32 + quad * 8];
#pragma unroll
      for (int mt = 0; mt < 2; ++mt)
#pragma unroll
        for (int nt = 0; nt < 4; ++nt)
          acc[mt][nt] = __builtin_amdgcn_mfma_f32_16x16x32_bf16(af[mt], bf[nt], acc[mt][nt], 0, 0, 0);
    }
  }

#pragma unroll
  for (int nt = 0; nt < 4; ++nt) {
    const int col = c0 + nc + nt * 16 + m16;
    const float bias = bo[col];
#pragma unroll
    for (int mt = 0; mt < 2; ++mt)
#pragma unroll
      for (int rr = 0; rr < 4; ++rr)
        out[(r0 + mr + mt * 16 + quad * 4 + rr) * 1024 + col] = acc[mt][nt][rr] + bias;
  }
}

// ---------------- launch ----------------
extern "C" void kernel_launch(void* const* d_in, const int* in_sizes, int n_in,
                              void* d_out, int out_size, void* d_ws, size_t ws_size,
                              hipStream_t stream) {
  const float* query = (const float*)d_in[0];
  const float* key = (const float*)d_in[1];
  const float* value = (const float*)d_in[2];
  const int* mask = (const int*)d_in[3];
  const float* Wq = (const float*)d_in[4];
  const float* Wk = (const float*)d_in[5];
  const float* Wv = (const float*)d_in[6];
  const float* Wo = (const float*)d_in[7];
  const float* bo = (const float*)d_in[8];
  float* out = (float*)d_out;

  char* ws = (char*)d_ws;
  short* Qp = (short*)(ws);
  short* Kp = (short*)(ws + 8388608);
  short* Vt = (short*)(ws + 16777216);
  short* Ob = (short*)(ws + 25165824);
  short* Wob = (short*)(ws + 33554432);
  unsigned long long* mpk = (unsigned long long*)(ws + 35651584);  // 1 MB

  prep<<<12288, 256, 0, stream>>>(query, key, value, Wq, Wk, Wv, Wo, mask,
                                  Qp, Kp, Vt, Wob, mpk);
  flash2<<<512, 512, 0, stream>>>(Qp, Kp, Vt, mpk, Ob);
  outproj<<<512, 256, 0, stream>>>(Ob, Wob, bo, out);
}

// Round 5
// 247.819 us; speedup vs baseline: 1.0559x; 1.0224x over previous
//
#include <hip/hip_runtime.h>

typedef __attribute__((ext_vector_type(8))) short short8;
typedef __attribute__((ext_vector_type(4))) float f32x4;
typedef __attribute__((ext_vector_type(2))) int int2v;
typedef __attribute__((ext_vector_type(4))) int int4v;

__device__ __forceinline__ short f2bf(float f) {
  unsigned u = __builtin_bit_cast(unsigned, f);
  u += 0x7fff + ((u >> 16) & 1);  // RNE
  return (short)(u >> 16);
}

__device__ __forceinline__ int pk2bf(float lo, float hi) {
#if defined(__gfx950__) && __has_builtin(__builtin_amdgcn_cvt_pk_bf16_f32)
  typedef __attribute__((ext_vector_type(2))) __bf16 bf16x2;
  bf16x2 v = __builtin_amdgcn_cvt_pk_bf16_f32(lo, hi);
  return __builtin_bit_cast(int, v);
#else
  return (int)(unsigned short)(short)f2bf(lo) | (((int)f2bf(hi)) << 16);
#endif
}

__device__ __forceinline__ short8 pack8(f32x4 a, f32x4 b) {
  int4v t;
  t.x = pk2bf(a[0], a[1]);
  t.y = pk2bf(a[2], a[3]);
  t.z = pk2bf(b[0], b[1]);
  t.w = pk2bf(b[2], b[3]);
  return __builtin_bit_cast(short8, t);
}

__device__ __forceinline__ float fand(float p, int m) {
  return __builtin_bit_cast(float, __builtin_bit_cast(int, p) & m);
}

__device__ __forceinline__ int bmask(unsigned nib, int bit) {
#if __has_builtin(__builtin_amdgcn_sbfe)
  return __builtin_amdgcn_sbfe((int)nib, bit, 1);  // 0 or 0xFFFFFFFF
#else
  return -(int)((nib >> bit) & 1);
#endif
}

__device__ __forceinline__ float fexp2(float x) {
#if __has_builtin(__builtin_amdgcn_exp2f)
  return __builtin_amdgcn_exp2f(x);
#else
  return exp2f(x);
#endif
}

// async global->LDS, 16B per lane; LDS dest = wave-uniform base + lane*16
__device__ __forceinline__ void glds16(const short* g, short* lbase, int lane) {
#if __has_builtin(__builtin_amdgcn_global_load_lds)
  __builtin_amdgcn_global_load_lds(
      (const __attribute__((address_space(1))) unsigned int*)g,
      (__attribute__((address_space(3))) unsigned int*)lbase, 16, 0, 0);
#else
  *(short8*)(lbase + lane * 8) = *(const short8*)g;
#endif
}

// =============== prep: projections + Wo cvt + mask pack, one dispatch ===============
__global__ __launch_bounds__(256) void prep(const float* __restrict__ q,
                                            const float* __restrict__ k,
                                            const float* __restrict__ v,
                                            const float* __restrict__ Wq,
                                            const float* __restrict__ Wk,
                                            const float* __restrict__ Wv,
                                            const float* __restrict__ Wo,
                                            const int* __restrict__ mask,
                                            short* __restrict__ Qp,
                                            short* __restrict__ Kp,
                                            short* __restrict__ Vtp,
                                            short* __restrict__ Wob,
                                            unsigned long long* __restrict__ mpk) {
  const int bid = blockIdx.x;
  const int tid = threadIdx.x;

  if (bid >= 4096) {  // ---- mask pack: bit j = mask[.. + (j&3)*16 + (j>>2)] ----
#pragma unroll
    for (int it = 0; it < 4; ++it) {
      const int gid = ((bid - 4096) * 4 + it) * 256 + tid;
      const int base = gid & ~63, j = gid & 63;
      const int val = mask[base + ((j & 3) << 4) + (j >> 2)];
      const unsigned long long bal = __ballot(val != 0);
      if (j == 0) mpk[gid >> 6] = bal;
    }
    return;
  }
  if (bid >= 3072) {  // ---- Wo convert ----
    const int i = ((bid - 3072) * 256 + tid) * 4;
    const f32x4 x = *(const f32x4*)&Wo[i];
    int2v o;
    o.x = pk2bf(x[0], x[1]);
    o.y = pk2bf(x[2], x[3]);
    *(int2v*)&Wob[i] = o;
    return;
  }

  // ---- projection: Out = X @ W^T on a 64-row slab ----
  __shared__ short xt[64][72];
  __shared__ short ot[64][72];
  const int mode = bid >> 10;
  const int bt = bid & 1023;
  const float* X;
  const float* W;
  float scale;
  if (mode == 0) { X = q; W = Wq; scale = 0.045084220f; }  // log2(e)/32 folded into Q
  else if (mode == 1) { X = k; W = Wk; scale = 1.0f; }
  else { X = v; W = Wv; scale = 1.0f; }

  const int r0 = bt * 64;
  const int row = tid >> 2, seg = (tid & 3) * 16;
  const f32x4* xs = (const f32x4*)(X + (r0 + row) * 64 + seg);
  const f32x4 x0 = xs[0], x1 = xs[1], x2 = xs[2], x3 = xs[3];
  *(short8*)&xt[row][seg] = pack8(x0, x1);
  *(short8*)&xt[row][seg + 8] = pack8(x2, x3);
  __syncthreads();

  const int lane = tid & 63, wave = tid >> 6;
  const int m16 = lane & 15, quad = lane >> 4;

  const short8 a0 = *(const short8*)&xt[wave * 16 + m16][quad * 8];
  const short8 a1 = *(const short8*)&xt[wave * 16 + m16][32 + quad * 8];

  f32x4 acc[4];
#pragma unroll
  for (int nt = 0; nt < 4; ++nt) {
    const f32x4* wp0 = (const f32x4*)&W[(nt * 16 + m16) * 64 + quad * 8];
    const f32x4* wp1 = (const f32x4*)&W[(nt * 16 + m16) * 64 + 32 + quad * 8];
    const short8 b0 = pack8(wp0[0], wp0[1]);
    const short8 b1 = pack8(wp1[0], wp1[1]);
    f32x4 z = (f32x4){0.f, 0.f, 0.f, 0.f};
    z = __builtin_amdgcn_mfma_f32_16x16x32_bf16(a0, b0, z, 0, 0, 0);
    z = __builtin_amdgcn_mfma_f32_16x16x32_bf16(a1, b1, z, 0, 0, 0);
    acc[nt] = z;
  }

  if (mode != 2) {
#pragma unroll
    for (int nt = 0; nt < 4; ++nt)
#pragma unroll
      for (int r = 0; r < 4; ++r)
        ot[wave * 16 + quad * 4 + r][nt * 16 + m16] = f2bf(acc[nt][r] * scale);
  } else {
    // transposed + sigma-permuted: ot[d][sigma(key)], sigma = 16*quad + 4*r + wave
#pragma unroll
    for (int nt = 0; nt < 4; ++nt)
#pragma unroll
      for (int r = 0; r < 4; ++r)
        ot[nt * 16 + m16][16 * quad + 4 * r + wave] = f2bf(acc[nt][r]);
  }
  __syncthreads();

  const int orow = tid >> 2, opart = tid & 3;
  if (mode != 2) {
    short* dst = (mode == 0 ? Qp : Kp) + (r0 + orow) * 64 + opart * 16;
    *(short8*)&dst[0] = *(const short8*)&ot[orow][opart * 16];
    *(short8*)&dst[8] = *(const short8*)&ot[orow][opart * 16 + 8];
  } else {
    const int bh = r0 >> 11, s0 = r0 & 2047;
    short* dst = Vtp + bh * 131072 + orow * 2048 + s0 + opart * 16;
    *(short8*)&dst[0] = *(const short8*)&ot[orow][opart * 16];
    *(short8*)&dst[8] = *(const short8*)&ot[orow][opart * 16 + 8];
  }
}

// =============== flashp: 128 q-rows/block, double-buffered pipelined K/V ===========
// Qp (pre-scaled): [BH][2048][64]; Kp: [BH][2048][64]; Vt: [BH][64][2048] sigma-ordered;
// mpk: [B][2048][32] u64 sigma bits; O: [BH][2048][64] bf16.
// Per iter: barrier (drains last prefetch) -> prefetch tile i+1 -> compute tile i.
// Masks register-prefetched one tile ahead (no mid-iter vmcnt waits; vmcnt is FIFO).
__global__ __launch_bounds__(256) void flashp(const short* __restrict__ Qp,
                                              const short* __restrict__ Kp,
                                              const short* __restrict__ Vt,
                                              const unsigned long long* __restrict__ mpk,
                                              short* __restrict__ O) {
  __shared__ __attribute__((aligned(16))) short kt[2][4096];
  __shared__ __attribute__((aligned(16))) short vt[2][4096];
  __shared__ __attribute__((aligned(16))) short pt[128][72];
  const int tid = threadIdx.x;
  const int bid = blockIdx.x;
  const int local = bid >> 3;  // XCD-grouping: blocks with equal bid%8 share heads
  const int bh = (bid & 7) * 4 + (local >> 4);
  const int q0 = (local & 15) << 7;
  const int b = bh >> 4;
  const short* Qh = Qp + bh * 131072;
  const short* Kh = Kp + bh * 131072;
  const short* Vh = Vt + bh * 131072;
  const int lane = tid & 63, wave = tid >> 6;
  const int m16 = lane & 15, quad = lane >> 4;
  const int srow = lane >> 3, sj = (lane & 7) ^ srow;
  const int msh = m16 * 4;
  const int koff = m16 * 128 + ((quad ^ (m16 & 7)) * 16);

  short8 aq[2][2];
#pragma unroll
  for (int g = 0; g < 2; ++g)
#pragma unroll
    for (int h = 0; h < 2; ++h)
      aq[g][h] = *(const short8*)&Qh[(q0 + wave * 32 + g * 16 + m16) * 64 + h * 32 + quad * 8];

  const unsigned long long* mq = mpk + (b * 2048 + q0 + wave * 32 + quad * 4) * 32;

  float l[2][4];
  f32x4 oacc[2][4];
#pragma unroll
  for (int g = 0; g < 2; ++g)
#pragma unroll
    for (int r = 0; r < 4; ++r) l[g][r] = 0.f;
#pragma unroll
  for (int g = 0; g < 2; ++g)
#pragma unroll
    for (int dt = 0; dt < 4; ++dt) oacc[g][dt] = (f32x4){0.f, 0.f, 0.f, 0.f};

  auto stage = [&](int buf, int ka) {
#pragma unroll
    for (int t = 0; t < 2; ++t) {
      const int crow = wave * 16 + t * 8;
      glds16(Kh + (ka * 64 + crow + srow) * 64 + sj * 8, &kt[buf][crow * 64], lane);
      glds16(Vh + (crow + srow) * 2048 + ka * 64 + sj * 8, &vt[buf][crow * 64], lane);
    }
  };
  auto lmask = [&](unsigned long long (&mw)[2][4], int ka) {
#pragma unroll
    for (int g = 0; g < 2; ++g)
#pragma unroll
      for (int r = 0; r < 4; ++r) mw[g][r] = mq[g * 512 + r * 32 + ka];
  };

  auto body = [&](int ka, int buf, unsigned long long (&mwU)[2][4],
                  unsigned long long (&mwN)[2][4]) {
    __syncthreads();  // drains prefetch for tile ka; frees buf^1 for overwrite
    if (ka < 31) {
      stage(buf ^ 1, ka + 1);
      lmask(mwN, ka + 1);
    }

    // S = Q K^T
    f32x4 s[2][4];
#pragma unroll
    for (int nt = 0; nt < 4; ++nt) {
      const int o0 = nt * 2048 + koff;
      const short8 kb0 = *(const short8*)((const char*)&kt[buf][0] + o0);
      const short8 kb1 = *(const short8*)((const char*)&kt[buf][0] + (o0 ^ 64));
#pragma unroll
      for (int g = 0; g < 2; ++g) {
        f32x4 z = (f32x4){0.f, 0.f, 0.f, 0.f};
        z = __builtin_amdgcn_mfma_f32_16x16x32_bf16(aq[g][0], kb0, z, 0, 0, 0);
        z = __builtin_amdgcn_mfma_f32_16x16x32_bf16(aq[g][1], kb1, z, 0, 0, 0);
        s[g][nt] = z;
      }
    }

    // p = exp2(s) & mask (prefetched regs); per-lane l; P -> LDS (bf16, sigma cols)
#pragma unroll
    for (int g = 0; g < 2; ++g) {
#pragma unroll
      for (int r = 0; r < 4; ++r) {
        const unsigned nib = (unsigned)(mwU[g][r] >> msh) & 15u;
        const float p0 = fand(fexp2(s[g][0][r]), bmask(nib, 0));
        const float p1 = fand(fexp2(s[g][1][r]), bmask(nib, 1));
        const float p2 = fand(fexp2(s[g][2][r]), bmask(nib, 2));
        const float p3 = fand(fexp2(s[g][3][r]), bmask(nib, 3));
        l[g][r] += (p0 + p1) + (p2 + p3);
        int2v pp;
        pp.x = pk2bf(p0, p1);
        pp.y = pk2bf(p2, p3);
        *(int2v*)&pt[wave * 32 + g * 16 + quad * 4 + r][msh] = pp;
      }
    }

    // O += P V (same-wave DS ordering: no barrier for pt)
    short8 ap[2][2];
#pragma unroll
    for (int g = 0; g < 2; ++g)
#pragma unroll
      for (int h = 0; h < 2; ++h)
        ap[g][h] = *(const short8*)&pt[wave * 32 + g * 16 + m16][h * 32 + quad * 8];

#pragma unroll
    for (int dt = 0; dt < 4; ++dt) {
      const int o0 = dt * 2048 + koff;
      const short8 vb0 = *(const short8*)((const char*)&vt[buf][0] + o0);
      const short8 vb1 = *(const short8*)((const char*)&vt[buf][0] + (o0 ^ 64));
#pragma unroll
      for (int g = 0; g < 2; ++g) {
        f32x4 z = oacc[g][dt];
        z = __builtin_amdgcn_mfma_f32_16x16x32_bf16(ap[g][0], vb0, z, 0, 0, 0);
        z = __builtin_amdgcn_mfma_f32_16x16x32_bf16(ap[g][1], vb1, z, 0, 0, 0);
        oacc[g][dt] = z;
      }
    }
  };

  unsigned long long mwA[2][4], mwB[2][4];
  stage(0, 0);
  lmask(mwA, 0);

  for (int kk = 0; kk < 16; ++kk) {
    body(2 * kk, 0, mwA, mwB);
    body(2 * kk + 1, 1, mwB, mwA);
  }

  // l reduction (16-lane groups), normalize, coalesced O store via pt
#pragma unroll
  for (int g = 0; g < 2; ++g)
#pragma unroll
    for (int r = 0; r < 4; ++r) {
#pragma unroll
      for (int off = 1; off < 16; off <<= 1) l[g][r] += __shfl_xor(l[g][r], off, 16);
      const float inv = 1.0f / l[g][r];
#pragma unroll
      for (int dt = 0; dt < 4; ++dt)
        pt[wave * 32 + g * 16 + quad * 4 + r][dt * 16 + m16] = f2bf(oacc[g][dt][r] * inv);
    }

  const int orow = lane >> 1, opart = lane & 1;
  const int prow = wave * 32 + orow;
  short* og = O + (bh * 2048 + q0 + prow) * 64 + opart * 32;
#pragma unroll
  for (int c = 0; c < 32; c += 8)
    *(short8*)&og[c] = *(const short8*)&pt[prow][opart * 32 + c];
}

// =============== final projection: out = O @ Wo^T + bo, 64x128 tiles ===============
__global__ __launch_bounds__(256) void outproj(const short* __restrict__ Ob,
                                               const short* __restrict__ Wob,
                                               const float* __restrict__ bo,
                                               float* __restrict__ out) {
  __shared__ short at[64][72];
  __shared__ short bt[128][72];
  const int tid = threadIdx.x;
  const int bid = blockIdx.x;
  const int ct = bid >> 6, rt = bid & 63;  // ct-major: consecutive bids share Wob slab
  const int r0 = rt * 64, c0 = ct * 128;
  const int lane = tid & 63, wave = tid >> 6;
  const int mr = (wave >> 1) * 32, nc = (wave & 1) * 64;
  const int m16 = lane & 15, quad = lane >> 4;
  const int arow = tid >> 2, apart = tid & 3;
  const int brow = tid >> 1, bhalf = (tid & 1) * 32;

  f32x4 acc[2][4];
#pragma unroll
  for (int mt = 0; mt < 2; ++mt)
#pragma unroll
    for (int nt = 0; nt < 4; ++nt) acc[mt][nt] = (f32x4){0.f, 0.f, 0.f, 0.f};

  for (int kc = 0; kc < 16; ++kc) {
    __syncthreads();
    const short* ag = &Ob[(r0 + arow) * 1024 + kc * 64 + apart * 16];
    const short* bg = &Wob[(c0 + brow) * 1024 + kc * 64 + bhalf];
    *(short8*)&at[arow][apart * 16] = *(const short8*)&ag[0];
    *(short8*)&at[arow][apart * 16 + 8] = *(const short8*)&ag[8];
    *(short8*)&bt[brow][bhalf] = *(const short8*)&bg[0];
    *(short8*)&bt[brow][bhalf + 8] = *(const short8*)&bg[8];
    *(short8*)&bt[brow][bhalf + 16] = *(const short8*)&bg[16];
    *(short8*)&bt[brow][bhalf + 24] = *(const short8*)&bg[24];
    __syncthreads();

#pragma unroll
    for (int kh = 0; kh < 2; ++kh) {
      short8 af[2], bf[4];
#pragma unroll
      for (int i = 0; i < 2; ++i)
        af[i] = *(const short8*)&at[mr + i * 16 + m16][kh * 32 + quad * 8];
#pragma unroll
      for (int j = 0; j < 4; ++j)
        bf[j] = *(const short8*)&bt[nc + j * 16 + m16][kh * 32 + quad * 8];
#pragma unroll
      for (int mt = 0; mt < 2; ++mt)
#pragma unroll
        for (int nt = 0; nt < 4; ++nt)
          acc[mt][nt] = __builtin_amdgcn_mfma_f32_16x16x32_bf16(af[mt], bf[nt], acc[mt][nt], 0, 0, 0);
    }
  }

#pragma unroll
  for (int nt = 0; nt < 4; ++nt) {
    const int col = c0 + nc + nt * 16 + m16;
    const float bias = bo[col];
#pragma unroll
    for (int mt = 0; mt < 2; ++mt)
#pragma unroll
      for (int rr = 0; rr < 4; ++rr)
        out[(r0 + mr + mt * 16 + quad * 4 + rr) * 1024 + col] = acc[mt][nt][rr] + bias;
  }
}

// ---------------- launch ----------------
extern "C" void kernel_launch(void* const* d_in, const int* in_sizes, int n_in,
                              void* d_out, int out_size, void* d_ws, size_t ws_size,
                              hipStream_t stream) {
  const float* query = (const float*)d_in[0];
  const float* key = (const float*)d_in[1];
  const float* value = (const float*)d_in[2];
  const int* mask = (const int*)d_in[3];
  const float* Wq = (const float*)d_in[4];
  const float* Wk = (const float*)d_in[5];
  const float* Wv = (const float*)d_in[6];
  const float* Wo = (const float*)d_in[7];
  const float* bo = (const float*)d_in[8];
  float* out = (float*)d_out;

  char* ws = (char*)d_ws;
  short* Qp = (short*)(ws);
  short* Kp = (short*)(ws + 8388608);
  short* Vt = (short*)(ws + 16777216);
  short* Ob = (short*)(ws + 25165824);
  short* Wob = (short*)(ws + 33554432);
  unsigned long long* mpk = (unsigned long long*)(ws + 35651584);  // 1 MB

  prep<<<12288, 256, 0, stream>>>(query, key, value, Wq, Wk, Wv, Wo, mask,
                                  Qp, Kp, Vt, Wob, mpk);
  flashp<<<512, 256, 0, stream>>>(Qp, Kp, Vt, mpk, Ob);
  outproj<<<512, 256, 0, stream>>>(Ob, Wob, bo, out);
}

// Round 6
// 246.282 us; speedup vs baseline: 1.0625x; 1.0062x over previous
//
#include <hip/hip_runtime.h>

typedef __attribute__((ext_vector_type(8))) short short8;
typedef __attribute__((ext_vector_type(4))) float f32x4;
typedef __attribute__((ext_vector_type(2))) int int2v;
typedef __attribute__((ext_vector_type(4))) int int4v;

__device__ __forceinline__ short f2bf(float f) {
  unsigned u = __builtin_bit_cast(unsigned, f);
  u += 0x7fff + ((u >> 16) & 1);  // RNE
  return (short)(u >> 16);
}

__device__ __forceinline__ int pk2bf(float lo, float hi) {
#if defined(__gfx950__) && __has_builtin(__builtin_amdgcn_cvt_pk_bf16_f32)
  typedef __attribute__((ext_vector_type(2))) __bf16 bf16x2;
  bf16x2 v = __builtin_amdgcn_cvt_pk_bf16_f32(lo, hi);
  return __builtin_bit_cast(int, v);
#else
  return (int)(unsigned short)(short)f2bf(lo) | (((int)f2bf(hi)) << 16);
#endif
}

__device__ __forceinline__ short8 pack8(f32x4 a, f32x4 b) {
  int4v t;
  t.x = pk2bf(a[0], a[1]);
  t.y = pk2bf(a[2], a[3]);
  t.z = pk2bf(b[0], b[1]);
  t.w = pk2bf(b[2], b[3]);
  return __builtin_bit_cast(short8, t);
}

__device__ __forceinline__ float fand(float p, int m) {
  return __builtin_bit_cast(float, __builtin_bit_cast(int, p) & m);
}

__device__ __forceinline__ float fexp2(float x) {
#if __has_builtin(__builtin_amdgcn_exp2f)
  return __builtin_amdgcn_exp2f(x);
#else
  return exp2f(x);
#endif
}

__device__ __forceinline__ float bf2f(short s) {
  return __builtin_bit_cast(float, ((int)(unsigned short)s) << 16);
}

// async global->LDS, 16B per lane; LDS dest = wave-uniform base + lane*16
__device__ __forceinline__ void glds16(const short* g, short* lbase, int lane) {
#if __has_builtin(__builtin_amdgcn_global_load_lds)
  __builtin_amdgcn_global_load_lds(
      (const __attribute__((address_space(1))) unsigned int*)g,
      (__attribute__((address_space(3))) unsigned int*)lbase, 16, 0, 0);
#else
  *(short8*)(lbase + lane * 8) = *(const short8*)g;
#endif
}

// =============== prep: projections + Wo cvt + mask dword table ===============
// blocks [0,3072): per-head projections (mode 0=Q(scaled),1=K,2=V^T sigma)
// blocks [3072,4096): Wo fp32->bf16
// blocks [4096,5120): mmod[b][qblk][ka][wave*64+lane] dword:
//   bit (g*4+r)*4+bb = mask[b][qblk*128+wave*32+g*16+quad*4+r][ka*64+bb*16+m16] != 0
__global__ __launch_bounds__(256) void prep(const float* __restrict__ q,
                                            const float* __restrict__ k,
                                            const float* __restrict__ v,
                                            const float* __restrict__ Wq,
                                            const float* __restrict__ Wk,
                                            const float* __restrict__ Wv,
                                            const float* __restrict__ Wo,
                                            const int* __restrict__ mask,
                                            short* __restrict__ Qp,
                                            short* __restrict__ Kp,
                                            short* __restrict__ Vtp,
                                            short* __restrict__ Wob,
                                            unsigned* __restrict__ mmod) {
  const int bid = blockIdx.x;
  const int tid = threadIdx.x;

  if (bid >= 4096) {  // ---- mask dword table ----
    const int mb = bid - 4096;           // (b*16+qblk)*32 + ka
    const int ka = mb & 31, bq = mb >> 5;
    const int b_ = bq >> 4, qb = bq & 15;
    const int wv = tid >> 6, qd = (tid >> 4) & 3, m16_ = tid & 15;
    const int* mbase = mask + b_ * 4194304 + (qb * 128 + wv * 32) * 2048 + ka * 64 + m16_;
    unsigned d = 0;
#pragma unroll
    for (int p = 0; p < 8; ++p) {
      const int* mr = mbase + ((p >> 2) * 16 + qd * 4 + (p & 3)) * 2048;
#pragma unroll
      for (int bb = 0; bb < 4; ++bb)
        if (mr[bb * 16] != 0) d |= 1u << (p * 4 + bb);
    }
    mmod[mb * 256 + tid] = d;
    return;
  }
  if (bid >= 3072) {  // ---- Wo convert ----
    const int i = ((bid - 3072) * 256 + tid) * 4;
    const f32x4 x = *(const f32x4*)&Wo[i];
    int2v o;
    o.x = pk2bf(x[0], x[1]);
    o.y = pk2bf(x[2], x[3]);
    *(int2v*)&Wob[i] = o;
    return;
  }

  // ---- projection: Out = X @ W^T on a 64-row slab ----
  __shared__ short xt[64][72];
  __shared__ short ot[64][72];
  const int mode = bid >> 10;
  const int bt = bid & 1023;
  const float* X;
  const float* W;
  float scale;
  if (mode == 0) { X = q; W = Wq; scale = 0.045084220f; }  // log2(e)/32 folded into Q
  else if (mode == 1) { X = k; W = Wk; scale = 1.0f; }
  else { X = v; W = Wv; scale = 1.0f; }

  const int r0 = bt * 64;
  const int row = tid >> 2, seg = (tid & 3) * 16;
  const f32x4* xs = (const f32x4*)(X + (r0 + row) * 64 + seg);
  const f32x4 x0 = xs[0], x1 = xs[1], x2 = xs[2], x3 = xs[3];
  *(short8*)&xt[row][seg] = pack8(x0, x1);
  *(short8*)&xt[row][seg + 8] = pack8(x2, x3);
  __syncthreads();

  const int lane = tid & 63, wave = tid >> 6;
  const int m16 = lane & 15, quad = lane >> 4;

  const short8 a0 = *(const short8*)&xt[wave * 16 + m16][quad * 8];
  const short8 a1 = *(const short8*)&xt[wave * 16 + m16][32 + quad * 8];

  f32x4 acc[4];
#pragma unroll
  for (int nt = 0; nt < 4; ++nt) {
    const f32x4* wp0 = (const f32x4*)&W[(nt * 16 + m16) * 64 + quad * 8];
    const f32x4* wp1 = (const f32x4*)&W[(nt * 16 + m16) * 64 + 32 + quad * 8];
    const short8 b0 = pack8(wp0[0], wp0[1]);
    const short8 b1 = pack8(wp1[0], wp1[1]);
    f32x4 z = (f32x4){0.f, 0.f, 0.f, 0.f};
    z = __builtin_amdgcn_mfma_f32_16x16x32_bf16(a0, b0, z, 0, 0, 0);
    z = __builtin_amdgcn_mfma_f32_16x16x32_bf16(a1, b1, z, 0, 0, 0);
    acc[nt] = z;
  }

  if (mode != 2) {
#pragma unroll
    for (int nt = 0; nt < 4; ++nt)
#pragma unroll
      for (int r = 0; r < 4; ++r)
        ot[wave * 16 + quad * 4 + r][nt * 16 + m16] = f2bf(acc[nt][r] * scale);
  } else {
    // transposed + sigma-permuted: ot[d][sigma(key)], sigma = 16*quad + 4*r + wave
#pragma unroll
    for (int nt = 0; nt < 4; ++nt)
#pragma unroll
      for (int r = 0; r < 4; ++r)
        ot[nt * 16 + m16][16 * quad + 4 * r + wave] = f2bf(acc[nt][r]);
  }
  __syncthreads();

  const int orow = tid >> 2, opart = tid & 3;
  if (mode != 2) {
    short* dst = (mode == 0 ? Qp : Kp) + (r0 + orow) * 64 + opart * 16;
    *(short8*)&dst[0] = *(const short8*)&ot[orow][opart * 16];
    *(short8*)&dst[8] = *(const short8*)&ot[orow][opart * 16 + 8];
  } else {
    const int bh = r0 >> 11, s0 = r0 & 2047;
    short* dst = Vtp + bh * 131072 + orow * 2048 + s0 + opart * 16;
    *(short8*)&dst[0] = *(const short8*)&ot[orow][opart * 16];
    *(short8*)&dst[8] = *(const short8*)&ot[orow][opart * 16 + 8];
  }
}

// =============== flashs: 128 q-rows, K-split across block pairs, pipelined =========
// 1024 blocks: (bh, qblk, khalf). Each computes 16 k-tiles, outputs per-half
// normalized O (bf16) + per-half l. mmod: one dword per lane per tile.
__global__ __launch_bounds__(256) void flashs(const short* __restrict__ Qp,
                                              const short* __restrict__ Kp,
                                              const short* __restrict__ Vt,
                                              const unsigned* __restrict__ mmod,
                                              short* __restrict__ Opart,
                                              float* __restrict__ lpart) {
  __shared__ __attribute__((aligned(16))) short kt[2][4096];
  __shared__ __attribute__((aligned(16))) short vt[2][4096];
  __shared__ __attribute__((aligned(16))) short pt[128][72];
  const int tid = threadIdx.x;
  const int bid = blockIdx.x;
  const int local = bid >> 3;                 // XCD-grouping on bid&7
  const int khalf = local & 1;
  const int qblk = (local >> 1) & 15;
  const int bh = (bid & 7) * 4 + (local >> 5);
  const int q0 = qblk << 7;
  const int b = bh >> 4;
  const short* Qh = Qp + bh * 131072;
  const short* Kh = Kp + bh * 131072;
  const short* Vh = Vt + bh * 131072;
  const int lane = tid & 63, wave = tid >> 6;
  const int m16 = lane & 15, quad = lane >> 4;
  const int srow = lane >> 3, sj = (lane & 7) ^ srow;
  const int msh = m16 * 4;
  const int koff = m16 * 128 + ((quad ^ (m16 & 7)) * 16);
  const unsigned* mqb = mmod + (b * 16 + qblk) * 32 * 256 + tid;  // + ka*256

  short8 aq[2][2];
#pragma unroll
  for (int g = 0; g < 2; ++g)
#pragma unroll
    for (int h = 0; h < 2; ++h)
      aq[g][h] = *(const short8*)&Qh[(q0 + wave * 32 + g * 16 + m16) * 64 + h * 32 + quad * 8];

  float l[2][4];
  f32x4 oacc[2][4];
#pragma unroll
  for (int g = 0; g < 2; ++g)
#pragma unroll
    for (int r = 0; r < 4; ++r) l[g][r] = 0.f;
#pragma unroll
  for (int g = 0; g < 2; ++g)
#pragma unroll
    for (int dt = 0; dt < 4; ++dt) oacc[g][dt] = (f32x4){0.f, 0.f, 0.f, 0.f};

  const int kaEnd = khalf * 16 + 15;

  auto stage = [&](int buf, int ka) {
#pragma unroll
    for (int t = 0; t < 2; ++t) {
      const int crow = wave * 16 + t * 8;
      glds16(Kh + (ka * 64 + crow + srow) * 64 + sj * 8, &kt[buf][crow * 64], lane);
      glds16(Vh + (crow + srow) * 2048 + ka * 64 + sj * 8, &vt[buf][crow * 64], lane);
    }
  };

  auto body = [&](int ka, int buf, unsigned mwU, unsigned& mwN) {
    __syncthreads();  // drains prefetch for tile ka; frees buf^1
    if (ka < kaEnd) {
      stage(buf ^ 1, ka + 1);
      mwN = mqb[(ka + 1) * 256];
    }

    // S = Q K^T
    f32x4 s[2][4];
#pragma unroll
    for (int nt = 0; nt < 4; ++nt) {
      const int o0 = nt * 2048 + koff;
      const short8 kb0 = *(const short8*)((const char*)&kt[buf][0] + o0);
      const short8 kb1 = *(const short8*)((const char*)&kt[buf][0] + (o0 ^ 64));
#pragma unroll
      for (int g = 0; g < 2; ++g) {
        f32x4 z = (f32x4){0.f, 0.f, 0.f, 0.f};
        z = __builtin_amdgcn_mfma_f32_16x16x32_bf16(aq[g][0], kb0, z, 0, 0, 0);
        z = __builtin_amdgcn_mfma_f32_16x16x32_bf16(aq[g][1], kb1, z, 0, 0, 0);
        s[g][nt] = z;
      }
    }

    // p = exp2(s) masked via dword bits; per-lane l; P -> LDS (bf16, sigma cols)
#pragma unroll
    for (int g = 0; g < 2; ++g) {
#pragma unroll
      for (int r = 0; r < 4; ++r) {
        const int pb = (g * 4 + r) * 4;
        float p[4];
#pragma unroll
        for (int nt = 0; nt < 4; ++nt) {
          const int m = ((int)(mwU << (31 - (pb + nt)))) >> 31;  // 0 or -1
          p[nt] = fand(fexp2(s[g][nt][r]), m);
        }
        l[g][r] += (p[0] + p[1]) + (p[2] + p[3]);
        int2v pp;
        pp.x = pk2bf(p[0], p[1]);
        pp.y = pk2bf(p[2], p[3]);
        *(int2v*)&pt[wave * 32 + g * 16 + quad * 4 + r][msh] = pp;
      }
    }

    // O += P V (same-wave DS ordering: no barrier for pt)
    short8 ap[2][2];
#pragma unroll
    for (int g = 0; g < 2; ++g)
#pragma unroll
      for (int h = 0; h < 2; ++h)
        ap[g][h] = *(const short8*)&pt[wave * 32 + g * 16 + m16][h * 32 + quad * 8];

#pragma unroll
    for (int dt = 0; dt < 4; ++dt) {
      const int o0 = dt * 2048 + koff;
      const short8 vb0 = *(const short8*)((const char*)&vt[buf][0] + o0);
      const short8 vb1 = *(const short8*)((const char*)&vt[buf][0] + (o0 ^ 64));
#pragma unroll
      for (int g = 0; g < 2; ++g) {
        f32x4 z = oacc[g][dt];
        z = __builtin_amdgcn_mfma_f32_16x16x32_bf16(ap[g][0], vb0, z, 0, 0, 0);
        z = __builtin_amdgcn_mfma_f32_16x16x32_bf16(ap[g][1], vb1, z, 0, 0, 0);
        oacc[g][dt] = z;
      }
    }
  };

  unsigned mwA, mwB = 0;
  const int ka0 = khalf * 16;
  stage(0, ka0);
  mwA = mqb[ka0 * 256];

  for (int kk = 0; kk < 8; ++kk) {
    body(ka0 + 2 * kk, 0, mwA, mwB);
    body(ka0 + 2 * kk + 1, 1, mwB, mwA);
  }

  // per-half l reduction, normalize by own l, store O half + l half
  short* Oh = Opart + khalf * 4194304;
  float* lh = lpart + khalf * 65536;
#pragma unroll
  for (int g = 0; g < 2; ++g)
#pragma unroll
    for (int r = 0; r < 4; ++r) {
#pragma unroll
      for (int off = 1; off < 16; off <<= 1) l[g][r] += __shfl_xor(l[g][r], off, 16);
      const float inv = 1.0f / l[g][r];
#pragma unroll
      for (int dt = 0; dt < 4; ++dt)
        pt[wave * 32 + g * 16 + quad * 4 + r][dt * 16 + m16] = f2bf(oacc[g][dt][r] * inv);
      if (m16 == 0) lh[bh * 2048 + q0 + wave * 32 + g * 16 + quad * 4 + r] = l[g][r];
    }

  const int orow = lane >> 1, opart = lane & 1;
  const int prow = wave * 32 + orow;
  short* og = Oh + (bh * 2048 + q0 + prow) * 64 + opart * 32;
#pragma unroll
  for (int c = 0; c < 32; c += 8)
    *(short8*)&og[c] = *(const short8*)&pt[prow][opart * 32 + c];
}

// =============== combineO: Ob = w1*O0 + w2*O1 (convex, per-row l weights) ==========
__global__ __launch_bounds__(256) void combineO(const short* __restrict__ O0,
                                                const short* __restrict__ O1,
                                                const float* __restrict__ lp,
                                                short* __restrict__ Ob) {
  const int gid = blockIdx.x * 256 + threadIdx.x;
  const int e0 = gid * 8;
  const int row = e0 >> 6;
  const float l1 = lp[row], l2 = lp[65536 + row];
  const float is = 1.0f / (l1 + l2);
  const float w1 = l1 * is, w2 = l2 * is;
  const short8 a = *(const short8*)&O0[e0];
  const short8 c = *(const short8*)&O1[e0];
  float f[8];
#pragma unroll
  for (int j = 0; j < 8; ++j) f[j] = w1 * bf2f(a[j]) + w2 * bf2f(c[j]);
  int4v o;
  o.x = pk2bf(f[0], f[1]);
  o.y = pk2bf(f[2], f[3]);
  o.z = pk2bf(f[4], f[5]);
  o.w = pk2bf(f[6], f[7]);
  *(short8*)&Ob[e0] = __builtin_bit_cast(short8, o);
}

// =============== final projection: out = O @ Wo^T + bo, 64x128 tiles ===============
__global__ __launch_bounds__(256) void outproj(const short* __restrict__ Ob,
                                               const short* __restrict__ Wob,
                                               const float* __restrict__ bo,
                                               float* __restrict__ out) {
  __shared__ short at[64][72];
  __shared__ short bt[128][72];
  const int tid = threadIdx.x;
  const int bid = blockIdx.x;
  const int ct = bid >> 6, rt = bid & 63;
  const int r0 = rt * 64, c0 = ct * 128;
  const int lane = tid & 63, wave = tid >> 6;
  const int mr = (wave >> 1) * 32, nc = (wave & 1) * 64;
  const int m16 = lane & 15, quad = lane >> 4;
  const int arow = tid >> 2, apart = tid & 3;
  const int brow = tid >> 1, bhalf = (tid & 1) * 32;

  f32x4 acc[2][4];
#pragma unroll
  for (int mt = 0; mt < 2; ++mt)
#pragma unroll
    for (int nt = 0; nt < 4; ++nt) acc[mt][nt] = (f32x4){0.f, 0.f, 0.f, 0.f};

  for (int kc = 0; kc < 16; ++kc) {
    __syncthreads();
    const short* ag = &Ob[(r0 + arow) * 1024 + kc * 64 + apart * 16];
    const short* bg = &Wob[(c0 + brow) * 1024 + kc * 64 + bhalf];
    *(short8*)&at[arow][apart * 16] = *(const short8*)&ag[0];
    *(short8*)&at[arow][apart * 16 + 8] = *(const short8*)&ag[8];
    *(short8*)&bt[brow][bhalf] = *(const short8*)&bg[0];
    *(short8*)&bt[brow][bhalf + 8] = *(const short8*)&bg[8];
    *(short8*)&bt[brow][bhalf + 16] = *(const short8*)&bg[16];
    *(short8*)&bt[brow][bhalf + 24] = *(const short8*)&bg[24];
    __syncthreads();

#pragma unroll
    for (int kh = 0; kh < 2; ++kh) {
      short8 af[2], bf[4];
#pragma unroll
      for (int i = 0; i < 2; ++i)
        af[i] = *(const short8*)&at[mr + i * 16 + m16][kh * 32 + quad * 8];
#pragma unroll
      for (int j = 0; j < 4; ++j)
        bf[j] = *(const short8*)&bt[nc + j * 16 + m16][kh * 32 + quad * 8];
#pragma unroll
      for (int mt = 0; mt < 2; ++mt)
#pragma unroll
        for (int nt = 0; nt < 4; ++nt)
          acc[mt][nt] = __builtin_amdgcn_mfma_f32_16x16x32_bf16(af[mt], bf[nt], acc[mt][nt], 0, 0, 0);
    }
  }

#pragma unroll
  for (int nt = 0; nt < 4; ++nt) {
    const int col = c0 + nc + nt * 16 + m16;
    const float bias = bo[col];
#pragma unroll
    for (int mt = 0; mt < 2; ++mt)
#pragma unroll
      for (int rr = 0; rr < 4; ++rr)
        out[(r0 + mr + mt * 16 + quad * 4 + rr) * 1024 + col] = acc[mt][nt][rr] + bias;
  }
}

// ---------------- launch ----------------
extern "C" void kernel_launch(void* const* d_in, const int* in_sizes, int n_in,
                              void* d_out, int out_size, void* d_ws, size_t ws_size,
                              hipStream_t stream) {
  const float* query = (const float*)d_in[0];
  const float* key = (const float*)d_in[1];
  const float* value = (const float*)d_in[2];
  const int* mask = (const int*)d_in[3];
  const float* Wq = (const float*)d_in[4];
  const float* Wk = (const float*)d_in[5];
  const float* Wv = (const float*)d_in[6];
  const float* Wo = (const float*)d_in[7];
  const float* bo = (const float*)d_in[8];
  float* out = (float*)d_out;

  char* ws = (char*)d_ws;
  short* Qp = (short*)(ws);                       // 8 MB (reused as Ob after flash)
  short* Kp = (short*)(ws + 8388608);             // 8 MB
  short* Vt = (short*)(ws + 16777216);            // 8 MB (+pad)
  short* Opart = (short*)(ws + 25165824);         // 2 x 8 MB halves
  short* Wob = (short*)(ws + 41943040);           // 2 MB
  float* lp = (float*)(ws + 44040192);            // 512 KB
  unsigned* mmod = (unsigned*)(ws + 44564480);    // 1 MB
  short* Ob = Qp;                                 // alias: Qp dead after flashs

  prep<<<5120, 256, 0, stream>>>(query, key, value, Wq, Wk, Wv, Wo, mask,
                                 Qp, Kp, Vt, Wob, mmod);
  flashs<<<1024, 256, 0, stream>>>(Qp, Kp, Vt, mmod, Opart, lp);
  combineO<<<2048, 256, 0, stream>>>(Opart, Opart + 4194304, lp, Ob);
  outproj<<<512, 256, 0, stream>>>(Ob, Wob, bo, out);
}